// Round 6
// baseline (418.191 us; speedup 1.0000x reference)
//
#include <hip/hip_runtime.h>
#include <hip/hip_bf16.h>

#define NB 16
#define CIN 512
#define NPIX 4096
#define CM 128
#define M3 384

typedef float f32x4 __attribute__((ext_vector_type(4)));
typedef short s16x8 __attribute__((ext_vector_type(8)));

static __device__ __forceinline__ unsigned short bfr(float f) {
  unsigned u = __builtin_bit_cast(unsigned, f);
  u = (u + 0x7fffu + ((u >> 16) & 1u)) >> 16;   // RNE round to bf16
  return (unsigned short)u;
}
static __device__ __forceinline__ short f2bs(float f) { return (short)bfr(f); }

// ---------------- weight prep: [384][512] bf16, 16B-chunk XOR-swizzled per 64-k block ----
__global__ __launch_bounds__(512) void kw_cast(const float* __restrict__ wA,
                                               const float* __restrict__ wB,
                                               const float* __restrict__ wV,
                                               short* __restrict__ Wc) {
  int row = blockIdx.x;
  int k = threadIdx.x;
  const float* src = (row < 128) ? (wA + row * CIN)
                   : ((row < 256) ? (wB + (row - 128) * CIN) : (wV + (row - 256) * CIN));
  float v = src[k];
  int c = k >> 6, p = (k >> 3) & 7, j = k & 7;
  // stored[row][c*64 + (p^s)*8 + j] = W[row][c*64 + p*8 + j]
  Wc[row * CIN + c * 64 + (((p ^ (row & 7)) << 3)) + j] = f2bs(v);
}

// ---------------- K1: A/B/V GEMM + softmax(B,V) + partial gd, fused ----------------------
// grid 256 = 16 batches x 16 blocks; block owns 4 column tiles of 64 (256 cols)
__global__ __launch_bounds__(512) void k1_abv(
    const float* __restrict__ x, const short* __restrict__ Wc,
    const float* __restrict__ bA, const float* __restrict__ bB, const float* __restrict__ bV,
    short* __restrict__ Pv,    // [16][4096][128] bf16, chunk-swizzled
    float* __restrict__ gdp)   // [16][16][128][128] f32 partials
{
  __shared__ __attribute__((aligned(16))) char smem[124928];
  short* Wlds = (short*)smem;              // [384][64] bf16 (content swizzled)  49152 B
  short* Xlds = (short*)(smem + 49152);    // [64][64]  bf16 (content swizzled)   8192 B
  float* Tlds = (float*)smem;              // [384][68] f32  (aliases staging)  104448 B
  short* Plds = (short*)(smem + 104448);   // [128][72] bf16                     18432 B
  float* red  = (float*)(smem + 122880);   // [8][64] f32                         2048 B

  const int tid  = threadIdx.x;
  const int lane = tid & 63;
  const int wv   = tid >> 6;               // wave 0..7
  const int b    = blockIdx.x >> 4;
  const int blk  = blockIdx.x & 15;
  const float* xb = x + (size_t)b * CIN * NPIX;

  f32x4 gacc[8];
  #pragma unroll
  for (int i = 0; i < 8; ++i) gacc[i] = (f32x4){0.f, 0.f, 0.f, 0.f};

  for (int t = 0; t < 4; ++t) {
    const int n0 = (blk * 4 + t) * 64;
    f32x4 acc[3][4];
    #pragma unroll
    for (int fr = 0; fr < 3; ++fr)
      #pragma unroll
      for (int cf = 0; cf < 4; ++cf) acc[fr][cf] = (f32x4){0.f, 0.f, 0.f, 0.f};

    for (int ks = 0; ks < 8; ++ks) {       // K-step of 64 over K=512
      const int k0 = ks * 64;
      __syncthreads();
      // stage W tile [384][64] (already-swizzled content, linear copy)
      #pragma unroll
      for (int j = 0; j < 6; ++j) {
        int g = tid + j * 512;             // 16B chunk id, 0..3071
        int row = g >> 3, sp = g & 7;
        *(int4*)(Wlds + row * 64 + sp * 8) = *(const int4*)(Wc + row * CIN + k0 + sp * 8);
      }
      // stage X tile: wave wv loads k rows k0+wv*8..+7, lane = column; cvt f32->bf16; swizzled write
      {
        const float* xs = xb + (size_t)(k0 + wv * 8) * NPIX + n0 + lane;
        float xvv[8];
        #pragma unroll
        for (int i = 0; i < 8; ++i) xvv[i] = xs[(size_t)i * NPIX];
        s16x8 xv16;
        #pragma unroll
        for (int i = 0; i < 8; ++i) xv16[i] = f2bs(xvv[i]);
        int sp = wv ^ (lane & 7);
        *(s16x8*)(Xlds + lane * 64 + sp * 8) = xv16;
      }
      __syncthreads();
      // MFMA: wave wv owns rows wv*48..+47 (3 frags) x 4 col frags
      #pragma unroll
      for (int kk = 0; kk < 2; ++kk) {
        int q = kk * 4 + (lane >> 4);      // 16B slot within 64-k chunk
        s16x8 bfrag[4];
        #pragma unroll
        for (int cf = 0; cf < 4; ++cf) {
          int colx = cf * 16 + (lane & 15);
          bfrag[cf] = *(const s16x8*)(Xlds + colx * 64 + ((q ^ (colx & 7)) << 3));
        }
        #pragma unroll
        for (int fr = 0; fr < 3; ++fr) {
          int row = wv * 48 + fr * 16 + (lane & 15);
          s16x8 afrag = *(const s16x8*)(Wlds + row * 64 + ((q ^ (row & 7)) << 3));
          #pragma unroll
          for (int cf = 0; cf < 4; ++cf)
            acc[fr][cf] = __builtin_amdgcn_mfma_f32_16x16x32_bf16(afrag, bfrag[cf], acc[fr][cf], 0, 0, 0);
        }
      }
    }
    __syncthreads();
    // epilogue: acc -> Tlds (f32) + bias.  C layout: col=lane&15, row=(lane>>4)*4+reg
    #pragma unroll
    for (int fr = 0; fr < 3; ++fr) {
      #pragma unroll
      for (int i = 0; i < 4; ++i) {
        int r = wv * 48 + fr * 16 + (lane >> 4) * 4 + i;
        float bias = (r < 128) ? bA[r] : ((r < 256) ? bB[r - 128] : bV[r - 256]);
        #pragma unroll
        for (int cf = 0; cf < 4; ++cf) {
          int colx = cf * 16 + (lane & 15);
          Tlds[r * 68 + colx] = acc[fr][cf][i] + bias;
        }
      }
    }
    __syncthreads();
    // column softmax over 128 channels for B (rows 128..255) and V (rows 256..383)
    {
      int col = tid & 63, g = tid >> 6;    // 8 groups of 16 rows per column
      #pragma unroll
      for (int s = 0; s < 2; ++s) {
        int rb = 128 + s * 128 + g * 16;
        float e[16];
        float m = -1e30f;
        #pragma unroll
        for (int i = 0; i < 16; ++i) { e[i] = Tlds[(rb + i) * 68 + col]; m = fmaxf(m, e[i]); }
        red[g * 64 + col] = m;
        __syncthreads();
        float M = red[col];
        #pragma unroll
        for (int jj = 1; jj < 8; ++jj) M = fmaxf(M, red[jj * 64 + col]);
        float sum = 0.f;
        #pragma unroll
        for (int i = 0; i < 16; ++i) { e[i] = __expf(e[i] - M); sum += e[i]; }
        __syncthreads();
        red[g * 64 + col] = sum;
        __syncthreads();
        float S = red[col];
        #pragma unroll
        for (int jj = 1; jj < 8; ++jj) S += red[jj * 64 + col];
        float rinv = 1.f / S;
        if (s == 0) {
          // P_B -> LDS [k2][72] bf16 (row-major along n for gd B-operand)
          #pragma unroll
          for (int i = 0; i < 16; ++i) Plds[(g * 16 + i) * 72 + col] = f2bs(e[i] * rinv);
        } else {
          // P_V -> global, transposed [n][128], 16B-chunk swizzled by n&15
          int pk[8];
          #pragma unroll
          for (int i = 0; i < 8; ++i)
            pk[i] = (int)bfr(e[2 * i] * rinv) | ((int)bfr(e[2 * i + 1] * rinv) << 16);
          int4 v0 = make_int4(pk[0], pk[1], pk[2], pk[3]);
          int4 v1 = make_int4(pk[4], pk[5], pk[6], pk[7]);
          size_t basep = (((size_t)b) * NPIX + (size_t)(n0 + col)) * CM;
          int nm = col & 15;               // (n0+col)&15 == col&15 (n0 multiple of 64)
          *(int4*)(Pv + basep + (size_t)((((2 * g) ^ nm)) << 3)) = v0;
          *(int4*)(Pv + basep + (size_t)((((2 * g + 1) ^ nm)) << 3)) = v1;
        }
        __syncthreads();
      }
    }
    // partial gd += A_tile @ P_B^T   (K = 64 columns, 2 mfma steps)
    #pragma unroll
    for (int nb = 0; nb < 2; ++nb) {
      int rowm  = wv * 16 + (lane & 15);
      int nbase = nb * 32 + (lane >> 4) * 8;
      s16x8 af;
      #pragma unroll
      for (int j = 0; j < 8; ++j) af[j] = f2bs(Tlds[rowm * 68 + nbase + j]);
      #pragma unroll
      for (int cf = 0; cf < 8; ++cf) {
        int k2 = cf * 16 + (lane & 15);
        s16x8 bf = *(const s16x8*)(Plds + k2 * 72 + nbase);
        gacc[cf] = __builtin_amdgcn_mfma_f32_16x16x32_bf16(af, bf, gacc[cf], 0, 0, 0);
      }
    }
    // next tile's staging is guarded by the loop-top __syncthreads
  }
  // write gd partial: wave wv owns rows wv*16..+15
  float* gp = gdp + (size_t)(b * 16 + blk) * (CM * CM);
  #pragma unroll
  for (int cf = 0; cf < 8; ++cf)
    #pragma unroll
    for (int i = 0; i < 4; ++i)
      gp[(wv * 16 + (lane >> 4) * 4 + i) * CM + cf * 16 + (lane & 15)] = gacc[cf][i];
}

// ---------------- K2: reduce 16 gd partials -> gd ----------------------------------------
__global__ __launch_bounds__(256) void k2_red(const float* __restrict__ gdp,
                                              float* __restrict__ gd) {
  int idx = blockIdx.x * 256 + threadIdx.x;      // 16 * 16384
  int b = idx >> 14;
  int r = idx & 16383;
  const float* p = gdp + ((size_t)b * 16) * 16384 + r;
  float s = 0.f;
  #pragma unroll
  for (int j = 0; j < 16; ++j) s += p[j * 16384];
  gd[idx] = s;
}

// ---------------- K3: WZ = wR @ gd  (f32 compute, bf16 swizzled store) --------------------
__global__ __launch_bounds__(256) void k3_wz(const float* __restrict__ wR,
                                             const float* __restrict__ gd,
                                             short* __restrict__ WZ) {
  int b  = blockIdx.x >> 5;
  int rt = blockIdx.x & 31;
  int t  = threadIdx.x;
  int k2 = t & 127;
  int ri = t >> 7;
  int r0 = rt * 16 + ri * 8;
  const float* gb = gd + (size_t)b * 16384 + k2;
  const float* wb = wR + (size_t)r0 * CM;
  float a[8] = {0.f, 0.f, 0.f, 0.f, 0.f, 0.f, 0.f, 0.f};
  for (int m = 0; m < CM; ++m) {
    float g = gb[(size_t)m * CM];
    #pragma unroll
    for (int i = 0; i < 8; ++i) a[i] += wb[i * CM + m] * g;
  }
  int qq = k2 >> 3;
  #pragma unroll
  for (int i = 0; i < 8; ++i) {
    int r = r0 + i;
    WZ[((size_t)b * CIN + r) * CM + (((qq ^ (r & 15)) << 3)) + (k2 & 7)] = f2bs(a[i]);
  }
}

// ---------------- K4: out = WZ @ P_V + bR ------------------------------------------------
// grid 2048 = 16 batches x 4 mtiles x 32 ntiles; 128x128 tile, K=128 single stage
__global__ __launch_bounds__(256) void k4_out(const short* __restrict__ WZ,
                                              const short* __restrict__ Pv,
                                              const float* __restrict__ bR,
                                              float* __restrict__ out) {
  __shared__ __attribute__((aligned(16))) short Wl[128 * 128];
  __shared__ __attribute__((aligned(16))) short Pl[128 * 128];
  int tid = threadIdx.x;
  int lane = tid & 63;
  int wv = tid >> 6;
  int bid = blockIdx.x;
  int b  = bid >> 7;
  int mt = (bid >> 5) & 3;
  int nt = bid & 31;
  const short* Wsrc = WZ + ((size_t)b * CIN + mt * 128) * CM;
  const short* Psrc = Pv + ((size_t)b * NPIX + nt * 128) * CM;
  #pragma unroll
  for (int j = 0; j < 8; ++j) {
    int g = tid + j * 256;
    *(int4*)(Wl + g * 8) = *(const int4*)(Wsrc + g * 8);
    *(int4*)(Pl + g * 8) = *(const int4*)(Psrc + g * 8);
  }
  __syncthreads();
  int wm = wv >> 1, wn = wv & 1;
  f32x4 acc[4][4];
  #pragma unroll
  for (int mf = 0; mf < 4; ++mf)
    #pragma unroll
    for (int nf = 0; nf < 4; ++nf) acc[mf][nf] = (f32x4){0.f, 0.f, 0.f, 0.f};
  #pragma unroll
  for (int ks = 0; ks < 4; ++ks) {
    int qq = ks * 4 + (lane >> 4);
    s16x8 af[4];
    #pragma unroll
    for (int mf = 0; mf < 4; ++mf) {
      int r = wm * 64 + mf * 16 + (lane & 15);
      af[mf] = *(const s16x8*)(Wl + r * 128 + ((qq ^ (r & 15)) << 3));
    }
    #pragma unroll
    for (int nf = 0; nf < 4; ++nf) {
      int n = wn * 64 + nf * 16 + (lane & 15);
      s16x8 bf = *(const s16x8*)(Pl + n * 128 + ((qq ^ (n & 15)) << 3));
      #pragma unroll
      for (int mf = 0; mf < 4; ++mf)
        acc[mf][nf] = __builtin_amdgcn_mfma_f32_16x16x32_bf16(af[mf], bf, acc[mf][nf], 0, 0, 0);
    }
  }
  float* ob = out + ((size_t)b * CIN + (size_t)mt * 128) * NPIX + (size_t)nt * 128;
  #pragma unroll
  for (int mf = 0; mf < 4; ++mf) {
    #pragma unroll
    for (int i = 0; i < 4; ++i) {
      int rl = wm * 64 + mf * 16 + (lane >> 4) * 4 + i;
      float bias = bR[mt * 128 + rl];
      #pragma unroll
      for (int nf = 0; nf < 4; ++nf) {
        int cl = wn * 64 + nf * 16 + (lane & 15);
        ob[(size_t)rl * NPIX + cl] = acc[mf][nf][i] + bias;
      }
    }
  }
}

extern "C" void kernel_launch(void* const* d_in, const int* in_sizes, int n_in,
                              void* d_out, int out_size, void* d_ws, size_t ws_size,
                              hipStream_t stream) {
  (void)in_sizes; (void)n_in; (void)out_size; (void)ws_size;
  const float* x  = (const float*)d_in[0];
  const float* wA = (const float*)d_in[1];
  const float* bA = (const float*)d_in[2];
  const float* wB = (const float*)d_in[3];
  const float* bB = (const float*)d_in[4];
  const float* wV = (const float*)d_in[5];
  const float* bV = (const float*)d_in[6];
  const float* wR = (const float*)d_in[7];
  const float* bR = (const float*)d_in[8];
  float* out = (float*)d_out;
  char* ws = (char*)d_ws;
  // workspace layout (37.1 MB total)
  short* Wc  = (short*)ws;                 // 393216 B
  short* Pv  = (short*)(ws + 393216);      // 16777216 B
  float* gdp = (float*)(ws + 17170432);    // 16777216 B
  float* gd  = (float*)(ws + 33947648);    // 1048576 B
  short* WZ  = (short*)(ws + 34996224);    // 2097152 B -> 37093376

  kw_cast<<<dim3(M3), dim3(512), 0, stream>>>(wA, wB, wV, Wc);
  k1_abv<<<dim3(256), dim3(512), 0, stream>>>(x, Wc, bA, bB, bV, Pv, gdp);
  k2_red<<<dim3(1024), dim3(256), 0, stream>>>(gdp, gd);
  k3_wz<<<dim3(512), dim3(256), 0, stream>>>(wR, gd, WZ);
  k4_out<<<dim3(2048), dim3(256), 0, stream>>>(WZ, Pv, bR, out);
}

// Round 8
// 402.511 us; speedup vs baseline: 1.0390x; 1.0390x over previous
//
#include <hip/hip_runtime.h>
#include <hip/hip_bf16.h>

#define NB 16
#define CIN 512
#define NPIX 4096
#define CM 128
#define M3 384

typedef float f32x4 __attribute__((ext_vector_type(4)));
typedef short s16x8 __attribute__((ext_vector_type(8)));

static __device__ __forceinline__ unsigned short bfr(float f) {
  unsigned u = __builtin_bit_cast(unsigned, f);
  u = (u + 0x7fffu + ((u >> 16) & 1u)) >> 16;   // RNE round to bf16
  return (unsigned short)u;
}
static __device__ __forceinline__ short f2bs(float f) { return (short)bfr(f); }

// ---------------- weight prep: [384][512] bf16 linear (A;B;V stacked) --------------------
__global__ __launch_bounds__(512) void kw_cast(const float* __restrict__ wA,
                                               const float* __restrict__ wB,
                                               const float* __restrict__ wV,
                                               short* __restrict__ Wc) {
  int row = blockIdx.x;
  int k = threadIdx.x;
  const float* src = (row < 128) ? (wA + row * CIN)
                   : ((row < 256) ? (wB + (row - 128) * CIN) : (wV + (row - 256) * CIN));
  Wc[row * CIN + k] = f2bs(src[k]);
}

// ---------------- K1 v2: A/B/V GEMM + register softmax + partial gd ----------------------
// grid 256 = 16 batches x 16 blocks; block owns 4 column tiles of 64 (256 cols)
// LDS 76 KB: Xlds 32K (half-K staging, aliased by Vlds 18.4K) + Alds 18.4K + Plds 18.4K
//            + red_m 4K + red_s 4K.  7 barriers/tile, no barrier inside K-MFMA loop.
__global__ __launch_bounds__(512) void k1_abv(
    const float* __restrict__ x, const short* __restrict__ Wc,
    const float* __restrict__ bA, const float* __restrict__ bB, const float* __restrict__ bV,
    short* __restrict__ Pv,    // [16][4096][128] bf16, chunk-swizzled by n&15
    float* __restrict__ gdp)   // [16][16][128][128] f32 partials
{
  __shared__ __attribute__((aligned(16))) char smem[77824];
  short* Xlds = (short*)smem;              // [64 cols][32 chunks of 8] bf16, swizzled  32768
  short* Vlds = (short*)smem;              // [128][72] bf16 (aliases Xlds)             18432
  short* Alds = (short*)(smem + 32768);    // [128][72] bf16                            18432
  short* Plds = (short*)(smem + 51200);    // [128][72] bf16                            18432
  float* red_m = (float*)(smem + 69632);   // [16][64] f32                               4096
  float* red_s = (float*)(smem + 73728);   // [16][64] f32                               4096

  const int tid  = threadIdx.x;
  const int lane = tid & 63;
  const int lr   = lane & 15;
  const int l4   = lane >> 4;
  const int wv   = tid >> 6;               // wave 0..7
  const int b    = blockIdx.x >> 4;
  const int blk  = blockIdx.x & 15;
  const float* xb = x + (size_t)b * CIN * NPIX;
  const int col_s = tid & 63;              // staging / vpack column
  const int kg    = tid >> 6;              // staging k-group

  // per-frag constants: frag fi = wv*3+fr owns rows [fi*16, fi*16+16)
  int fi[3], sec_[3];
  float bias_r[3][4];
  #pragma unroll
  for (int fr = 0; fr < 3; ++fr) {
    fi[fr] = wv * 3 + fr;
    sec_[fr] = fi[fr] >> 3;                // 0=A,1=B,2=V
    const float* bp = (sec_[fr] == 0) ? bA : ((sec_[fr] == 1) ? bB : bV);
    int rl = (fi[fr] & 7) * 16 + l4 * 4;
    #pragma unroll
    for (int i = 0; i < 4; ++i) bias_r[fr][i] = bp[rl + i];
  }

  f32x4 gacc[8];
  #pragma unroll
  for (int i = 0; i < 8; ++i) gacc[i] = (f32x4){0.f, 0.f, 0.f, 0.f};

  for (int t = 0; t < 4; ++t) {
    const int n0 = (blk * 4 + t) * 64;
    f32x4 acc[3][4];
    #pragma unroll
    for (int fr = 0; fr < 3; ++fr)
      #pragma unroll
      for (int cf = 0; cf < 4; ++cf) acc[fr][cf] = (f32x4){0.f, 0.f, 0.f, 0.f};

    __syncthreads();                                         // (1) Xlds free (prev vpack/mfma done)
    #pragma unroll
    for (int h = 0; h < 2; ++h) {
      // ---- stage half-K: 256 k's x 64 cols, one burst of 32 loads/thread ----
      {
        const float* xs = xb + (size_t)(h * 256 + kg * 32) * NPIX + n0 + col_s;
        #pragma unroll
        for (int j2 = 0; j2 < 4; ++j2) {
          float v[8];
          #pragma unroll
          for (int i = 0; i < 8; ++i) v[i] = xs[(size_t)(j2 * 8 + i) * NPIX];
          s16x8 c;
          #pragma unroll
          for (int i = 0; i < 8; ++i) c[i] = f2bs(v[i]);
          int kc = kg * 4 + j2;                              // chunk 0..31 (8 k's each)
          *(s16x8*)(Xlds + (col_s * 32 + (kc ^ (col_s & 31))) * 8) = c;
        }
      }
      __syncthreads();                                       // (2)/(4) staged
      // ---- K-MFMA: 8 x 32-k steps, no barriers; W frags straight from L2 ----
      for (int kc32 = 0; kc32 < 8; ++kc32) {
        int cb = kc32 * 4;
        s16x8 bfrag[4];
        #pragma unroll
        for (int cf = 0; cf < 4; ++cf) {
          int c2 = cf * 16 + lr;
          bfrag[cf] = *(const s16x8*)(Xlds + (c2 * 32 + ((cb + l4) ^ (c2 & 31))) * 8);
        }
        #pragma unroll
        for (int fr = 0; fr < 3; ++fr) {
          int row = fi[fr] * 16 + lr;
          s16x8 af = *(const s16x8*)(Wc + (size_t)row * CIN + h * 256 + kc32 * 32 + l4 * 8);
          #pragma unroll
          for (int cf = 0; cf < 4; ++cf)
            acc[fr][cf] = __builtin_amdgcn_mfma_f32_16x16x32_bf16(af, bfrag[cf], acc[fr][cf], 0, 0, 0);
        }
      }
      if (h == 0) __syncthreads();                           // (3) Xlds reads drained before restage
    }

    // ---- bias ----
    #pragma unroll
    for (int fr = 0; fr < 3; ++fr)
      #pragma unroll
      for (int cf = 0; cf < 4; ++cf)
        #pragma unroll
        for (int i = 0; i < 4; ++i) acc[fr][cf][i] += bias_r[fr][i];

    // ---- step1: A -> Alds bf16; B/V per-frag column max -> red_m ----
    #pragma unroll
    for (int fr = 0; fr < 3; ++fr) {
      if (sec_[fr] == 0) {
        #pragma unroll
        for (int cf = 0; cf < 4; ++cf)
          #pragma unroll
          for (int i = 0; i < 4; ++i)
            Alds[(fi[fr] * 16 + l4 * 4 + i) * 72 + cf * 16 + lr] = f2bs(acc[fr][cf][i]);
      } else {
        float pm[4];
        #pragma unroll
        for (int cf = 0; cf < 4; ++cf) {
          pm[cf] = fmaxf(fmaxf(acc[fr][cf][0], acc[fr][cf][1]),
                         fmaxf(acc[fr][cf][2], acc[fr][cf][3]));
          pm[cf] = fmaxf(pm[cf], __shfl_xor(pm[cf], 16));
          pm[cf] = fmaxf(pm[cf], __shfl_xor(pm[cf], 32));
        }
        if (l4 == 0) {
          #pragma unroll
          for (int cf = 0; cf < 4; ++cf)
            red_m[(fi[fr] - 8) * 64 + cf * 16 + lr] = pm[cf];
        }
      }
    }
    __syncthreads();                                         // (5)

    // ---- step2: combine max, exp in place, per-frag sums -> red_s ----
    #pragma unroll
    for (int fr = 0; fr < 3; ++fr) {
      if (sec_[fr] >= 1) {
        int base = (sec_[fr] == 1) ? 0 : 8;
        float ps[4];
        #pragma unroll
        for (int cf = 0; cf < 4; ++cf) {
          float M = red_m[base * 64 + cf * 16 + lr];
          #pragma unroll
          for (int j = 1; j < 8; ++j) M = fmaxf(M, red_m[(base + j) * 64 + cf * 16 + lr]);
          float s = 0.f;
          #pragma unroll
          for (int i = 0; i < 4; ++i) {
            float e = __expf(acc[fr][cf][i] - M);
            acc[fr][cf][i] = e;
            s += e;
          }
          ps[cf] = s;
        }
        #pragma unroll
        for (int cf = 0; cf < 4; ++cf) {
          ps[cf] += __shfl_xor(ps[cf], 16);
          ps[cf] += __shfl_xor(ps[cf], 32);
        }
        if (l4 == 0) {
          #pragma unroll
          for (int cf = 0; cf < 4; ++cf)
            red_s[(fi[fr] - 8) * 64 + cf * 16 + lr] = ps[cf];
        }
      }
    }
    __syncthreads();                                         // (6)

    // ---- step3: normalize, write P_B -> Plds, P_V -> Vlds (bf16) ----
    #pragma unroll
    for (int fr = 0; fr < 3; ++fr) {
      if (sec_[fr] >= 1) {
        int base = (sec_[fr] == 1) ? 0 : 8;
        short* dst = (sec_[fr] == 1) ? Plds : Vlds;
        int rbase = (fi[fr] - (sec_[fr] == 1 ? 8 : 16)) * 16 + l4 * 4;
        #pragma unroll
        for (int cf = 0; cf < 4; ++cf) {
          float S = red_s[base * 64 + cf * 16 + lr];
          #pragma unroll
          for (int j = 1; j < 8; ++j) S += red_s[(base + j) * 64 + cf * 16 + lr];
          float rinv = 1.f / S;
          #pragma unroll
          for (int i = 0; i < 4; ++i)
            dst[(rbase + i) * 72 + cf * 16 + lr] = f2bs(acc[fr][cf][i] * rinv);
        }
      }
    }
    __syncthreads();                                         // (7)

    // ---- step4: partial gd += A @ P_B^T ; pack+write P_V to global ----
    #pragma unroll
    for (int nb = 0; nb < 2; ++nb) {
      int rowm  = wv * 16 + lr;
      int nbase = nb * 32 + l4 * 8;
      s16x8 af = *(const s16x8*)(Alds + rowm * 72 + nbase);
      #pragma unroll
      for (int cf = 0; cf < 8; ++cf) {
        s16x8 bf = *(const s16x8*)(Plds + (cf * 16 + lr) * 72 + nbase);
        gacc[cf] = __builtin_amdgcn_mfma_f32_16x16x32_bf16(af, bf, gacc[cf], 0, 0, 0);
      }
    }
    {
      int pk[8];
      #pragma unroll
      for (int ii = 0; ii < 8; ++ii) {
        unsigned short lo = (unsigned short)Vlds[(kg * 16 + 2 * ii) * 72 + col_s];
        unsigned short hi = (unsigned short)Vlds[(kg * 16 + 2 * ii + 1) * 72 + col_s];
        pk[ii] = (int)lo | ((int)hi << 16);
      }
      int4 v0 = make_int4(pk[0], pk[1], pk[2], pk[3]);
      int4 v1 = make_int4(pk[4], pk[5], pk[6], pk[7]);
      size_t basep = (((size_t)b) * NPIX + (size_t)(n0 + col_s)) * CM;
      int nm = col_s & 15;
      *(int4*)(Pv + basep + (size_t)(((2 * kg) ^ nm) << 3)) = v0;
      *(int4*)(Pv + basep + (size_t)(((2 * kg + 1) ^ nm) << 3)) = v1;
    }
  }

  // write gd partial: wave wv owns rows wv*16..+15
  float* gp = gdp + (size_t)(b * 16 + blk) * (CM * CM);
  #pragma unroll
  for (int cf = 0; cf < 8; ++cf)
    #pragma unroll
    for (int i = 0; i < 4; ++i)
      gp[(wv * 16 + l4 * 4 + i) * CM + cf * 16 + lr] = gacc[cf][i];
}

// ---------------- K2: reduce 16 gd partials -> gd ----------------------------------------
__global__ __launch_bounds__(256) void k2_red(const float* __restrict__ gdp,
                                              float* __restrict__ gd) {
  int idx = blockIdx.x * 256 + threadIdx.x;      // 16 * 16384
  int b = idx >> 14;
  int r = idx & 16383;
  const float* p = gdp + ((size_t)b * 16) * 16384 + r;
  float s = 0.f;
  #pragma unroll
  for (int j = 0; j < 16; ++j) s += p[j * 16384];
  gd[idx] = s;
}

// ---------------- K3: WZ = wR @ gd  (f32 compute, bf16 swizzled store) --------------------
__global__ __launch_bounds__(256) void k3_wz(const float* __restrict__ wR,
                                             const float* __restrict__ gd,
                                             short* __restrict__ WZ) {
  int b  = blockIdx.x >> 5;
  int rt = blockIdx.x & 31;
  int t  = threadIdx.x;
  int k2 = t & 127;
  int ri = t >> 7;
  int r0 = rt * 16 + ri * 8;
  const float* gb = gd + (size_t)b * 16384 + k2;
  const float* wb = wR + (size_t)r0 * CM;
  float a[8] = {0.f, 0.f, 0.f, 0.f, 0.f, 0.f, 0.f, 0.f};
  for (int m = 0; m < CM; ++m) {
    float g = gb[(size_t)m * CM];
    #pragma unroll
    for (int i = 0; i < 8; ++i) a[i] += wb[i * CM + m] * g;
  }
  int qq = k2 >> 3;
  #pragma unroll
  for (int i = 0; i < 8; ++i) {
    int r = r0 + i;
    WZ[((size_t)b * CIN + r) * CM + (((qq ^ (r & 15)) << 3)) + (k2 & 7)] = f2bs(a[i]);
  }
}

// ---------------- K4: out = WZ @ P_V + bR ------------------------------------------------
// grid 2048 = 16 batches x 4 mtiles x 32 ntiles; 128x128 tile, K=128 single stage
__global__ __launch_bounds__(256) void k4_out(const short* __restrict__ WZ,
                                              const short* __restrict__ Pv,
                                              const float* __restrict__ bR,
                                              float* __restrict__ out) {
  __shared__ __attribute__((aligned(16))) short Wl[128 * 128];
  __shared__ __attribute__((aligned(16))) short Pl[128 * 128];
  int tid = threadIdx.x;
  int lane = tid & 63;
  int wv = tid >> 6;
  int bid = blockIdx.x;
  int b  = bid >> 7;
  int mt = (bid >> 5) & 3;
  int nt = bid & 31;
  const short* Wsrc = WZ + ((size_t)b * CIN + mt * 128) * CM;
  const short* Psrc = Pv + ((size_t)b * NPIX + nt * 128) * CM;
  #pragma unroll
  for (int j = 0; j < 8; ++j) {
    int g = tid + j * 256;
    *(int4*)(Wl + g * 8) = *(const int4*)(Wsrc + g * 8);
    *(int4*)(Pl + g * 8) = *(const int4*)(Psrc + g * 8);
  }
  __syncthreads();
  int wm = wv >> 1, wn = wv & 1;
  f32x4 acc[4][4];
  #pragma unroll
  for (int mf = 0; mf < 4; ++mf)
    #pragma unroll
    for (int nf = 0; nf < 4; ++nf) acc[mf][nf] = (f32x4){0.f, 0.f, 0.f, 0.f};
  #pragma unroll
  for (int ks = 0; ks < 4; ++ks) {
    int qq = ks * 4 + (lane >> 4);
    s16x8 af[4];
    #pragma unroll
    for (int mf = 0; mf < 4; ++mf) {
      int r = wm * 64 + mf * 16 + (lane & 15);
      af[mf] = *(const s16x8*)(Wl + r * 128 + ((qq ^ (r & 15)) << 3));
    }
    #pragma unroll
    for (int nf = 0; nf < 4; ++nf) {
      int n = wn * 64 + nf * 16 + (lane & 15);
      s16x8 bf = *(const s16x8*)(Pl + n * 128 + ((qq ^ (n & 15)) << 3));
      #pragma unroll
      for (int mf = 0; mf < 4; ++mf)
        acc[mf][nf] = __builtin_amdgcn_mfma_f32_16x16x32_bf16(af[mf], bf, acc[mf][nf], 0, 0, 0);
    }
  }
  float* ob = out + ((size_t)b * CIN + (size_t)mt * 128) * NPIX + (size_t)nt * 128;
  #pragma unroll
  for (int mf = 0; mf < 4; ++mf) {
    #pragma unroll
    for (int i = 0; i < 4; ++i) {
      int rl = wm * 64 + mf * 16 + (lane >> 4) * 4 + i;
      float bias = bR[mt * 128 + rl];
      #pragma unroll
      for (int nf = 0; nf < 4; ++nf) {
        int cl = wn * 64 + nf * 16 + (lane & 15);
        ob[(size_t)rl * NPIX + cl] = acc[mf][nf][i] + bias;
      }
    }
  }
}

extern "C" void kernel_launch(void* const* d_in, const int* in_sizes, int n_in,
                              void* d_out, int out_size, void* d_ws, size_t ws_size,
                              hipStream_t stream) {
  (void)in_sizes; (void)n_in; (void)out_size; (void)ws_size;
  const float* x  = (const float*)d_in[0];
  const float* wA = (const float*)d_in[1];
  const float* bA = (const float*)d_in[2];
  const float* wB = (const float*)d_in[3];
  const float* bB = (const float*)d_in[4];
  const float* wV = (const float*)d_in[5];
  const float* bV = (const float*)d_in[6];
  const float* wR = (const float*)d_in[7];
  const float* bR = (const float*)d_in[8];
  float* out = (float*)d_out;
  char* ws = (char*)d_ws;
  // workspace layout (37.1 MB total)
  short* Wc  = (short*)ws;                 // 393216 B
  short* Pv  = (short*)(ws + 393216);      // 16777216 B
  float* gdp = (float*)(ws + 17170432);    // 16777216 B
  float* gd  = (float*)(ws + 33947648);    // 1048576 B
  short* WZ  = (short*)(ws + 34996224);    // 2097152 B -> 37093376

  kw_cast<<<dim3(M3), dim3(512), 0, stream>>>(wA, wB, wV, Wc);
  k1_abv<<<dim3(256), dim3(512), 0, stream>>>(x, Wc, bA, bB, bV, Pv, gdp);
  k2_red<<<dim3(1024), dim3(256), 0, stream>>>(gdp, gd);
  k3_wz<<<dim3(512), dim3(256), 0, stream>>>(wR, gd, WZ);
  k4_out<<<dim3(2048), dim3(256), 0, stream>>>(WZ, Pv, bR, out);
}